// Round 2
// baseline (378.716 us; speedup 1.0000x reference)
//
#include <hip/hip_runtime.h>
#include <stdint.h>

// DiffLogic: 3-layer differentiable logic network.
// Round 8: attack gather latency in the fused kernel.
//  - Per-block gate metadata (leaf idx + packed coefs) is CONTIGUOUS ->
//    stage it into LDS with one coalesced burst; per-gate reads become
//    ~120cy LDS broadcasts instead of chained global loads (pc is 7MB,
//    missed the 4MB XCD L2 at ~600cy).
//  - Fully unroll the 8-gate loop: all 64 column-gather addresses known
//    after the barrier -> deep MLP instead of 2-deep serial chains.
//  - Gate math refactored to 3 FMA: b*(c3*a+c2) + (c1*a+c0).
//  - Softmax folded into prep (coef_kernel deleted, -1 dispatch, -3MB ws).

#define BATCH   256
#define IN_DIM  1024
#define WIDTH   64000
#define NGROUP  10
#define GSIZE   6400      // WIDTH / NGROUP
#define TAU     30.0f
#define NWAVE   16        // waves per block
#define GPW     8         // gates per wave
#define GPB     (NWAVE*GPW)   // 128 gates/block; 6400 % 128 == 0
#define NBLK    (WIDTH/GPB)   // 500

typedef unsigned short ushort_t;

static __device__ __forceinline__ float bf2f(ushort_t s) {
    return __uint_as_float((uint32_t)s << 16);
}
static __device__ __forceinline__ ushort_t f2bf(float f) {   // RNE
    uint32_t u = __float_as_uint(f);
    return (ushort_t)((u + 0x7fffu + ((u >> 16) & 1u)) >> 16);
}
// h = c0 + c1*a + c2*b + c3*(a*b) = b*(c3*a+c2) + (c1*a+c0)  -- 3 FMA/elem
static __device__ __forceinline__ float gate1(float4 c, float a, float b) {
    return fmaf(b, fmaf(c.w, a, c.z), fmaf(c.y, a, c.x));
}
static __device__ __forceinline__ float4 gate4(float4 c, float4 a, float4 b) {
    float4 r;
    r.x = gate1(c, a.x, b.x);
    r.y = gate1(c, a.y, b.y);
    r.z = gate1(c, a.z, b.z);
    r.w = gate1(c, a.w, b.w);
    return r;
}
static __device__ __forceinline__ float4 up4(ushort4 s) {
    return make_float4(bf2f(s.x), bf2f(s.y), bf2f(s.z), bf2f(s.w));
}

// ---------------------------------------------------------------- transpose
// x:(256,1024) f32 row-major -> xT:(1024,256) bf16
__global__ __launch_bounds__(256) void transpose_kernel(
    const float* __restrict__ x, ushort_t* __restrict__ xT)
{
    __shared__ float tile[64][65];
    const int c0 = (blockIdx.x & 15) * 64;
    const int b0 = (blockIdx.x >> 4) * 64;
    const int lt = threadIdx.x & 63;
    const int wt = threadIdx.x >> 6;
    for (int r = wt; r < 64; r += 4)
        tile[r][lt] = x[(b0 + r) * IN_DIM + c0 + lt];
    __syncthreads();
    for (int r = wt; r < 64; r += 4)
        xT[(c0 + r) * BATCH + b0 + lt] = f2bf(tile[lt][r]);
}

// ---------------------------------------------------------------- softmax coef
static __device__ __forceinline__ float4 softmax_coef(const float* __restrict__ w)
{
    const float4* w4 = (const float4*)w;
    float4 q0 = w4[0], q1 = w4[1], q2 = w4[2], q3 = w4[3];
    float p[16] = {q0.x,q0.y,q0.z,q0.w, q1.x,q1.y,q1.z,q1.w,
                   q2.x,q2.y,q2.z,q2.w, q3.x,q3.y,q3.z,q3.w};
    float m = p[0];
    #pragma unroll
    for (int i = 1; i < 16; ++i) m = fmaxf(m, p[i]);
    float s = 0.f;
    #pragma unroll
    for (int i = 0; i < 16; ++i) { p[i] = __expf(p[i] - m); s += p[i]; }
    const float inv = 1.0f / s;
    float c0 = (p[8]+p[9]+p[10]+p[11]+p[12]+p[13]+p[14]+p[15]) * inv;
    float c1 = (p[2]+p[3]+p[6]+p[7] - p[8]-p[9]-p[12]-p[13]) * inv;
    float c2 = (p[4]+p[5]+p[6]+p[7] - p[8]-p[9]-p[10]-p[11]) * inv;
    float c3 = (p[1]-p[2]-p[4]-2.f*p[6]-p[7]+p[8]+2.f*p[9]+p[11]+p[13]-p[14]) * inv;
    return make_float4(c0, c1, c2, c3);
}

// ---------------------------------------------------------------- tree prep
// One thread per final gate j: flatten its depth-3 tree into 8 leaf x-indices
// + 7 softmaxed coefficient float4s (contiguous per gate).
__global__ __launch_bounds__(256) void prep_kernel(
    const float* __restrict__ w1, const float* __restrict__ w2,
    const float* __restrict__ w3,
    const int* __restrict__ ia1, const int* __restrict__ ib1,
    const int* __restrict__ ia2, const int* __restrict__ ib2,
    const int* __restrict__ ia3, const int* __restrict__ ib3,
    int* __restrict__ leaf,        // [WIDTH][8]
    float4* __restrict__ pc)       // [WIDTH][7]
{
    const int j = blockIdx.x * 256 + threadIdx.x;
    if (j >= WIDTH) return;

    const int pa = ia3[j], pb = ib3[j];
    const int qaa = ia2[pa], qab = ib2[pa];
    const int qba = ia2[pb], qbb = ib2[pb];

    int* L = leaf + (size_t)j * 8;
    L[0] = ia1[qaa]; L[1] = ib1[qaa];
    L[2] = ia1[qab]; L[3] = ib1[qab];
    L[4] = ia1[qba]; L[5] = ib1[qba];
    L[6] = ia1[qbb]; L[7] = ib1[qbb];

    float4* P = pc + (size_t)j * 7;
    P[0] = softmax_coef(w1 + (size_t)qaa * 16);
    P[1] = softmax_coef(w1 + (size_t)qab * 16);
    P[2] = softmax_coef(w1 + (size_t)qba * 16);
    P[3] = softmax_coef(w1 + (size_t)qbb * 16);
    P[4] = softmax_coef(w2 + (size_t)pa * 16);
    P[5] = softmax_coef(w2 + (size_t)pb * 16);
    P[6] = softmax_coef(w3 + (size_t)j * 16);
}

// ---------------------------------------------------------------- fused net
// Block = 128 contiguous gates. Metadata staged to LDS in one coalesced burst;
// gate loop fully unrolled so all 64 column gathers per wave can be in flight.
__global__ __launch_bounds__(1024) void fused_kernel(
    const ushort_t* __restrict__ xT,
    const int*      __restrict__ leaf,
    const float4*   __restrict__ pc,
    float*          __restrict__ red_out)
{
    __shared__ int    sleaf[GPB * 8];        // 4 KB
    __shared__ float4 spc[GPB * 7];          // 14 KB
    __shared__ float4 sred[NWAVE][64];       // 16 KB

    const int tid = threadIdx.x;

    // ---- coalesced metadata stage (block's spans are contiguous)
    sleaf[tid] = leaf[(size_t)blockIdx.x * (GPB * 8) + tid];      // 1024 x 4B
    if (tid < GPB * 7)
        spc[tid] = pc[(size_t)blockIdx.x * (GPB * 7) + tid];      // 896 x 16B
    __syncthreads();

    const int lane = tid & 63;
    const int wave = tid >> 6;
    const int gbase = wave * GPW;            // gate index within block

    float4 acc = make_float4(0.f, 0.f, 0.f, 0.f);

    #pragma unroll
    for (int u = 0; u < GPW; ++u) {
        const int g = gbase + u;
        // LDS broadcast reads (all lanes same addr) -> readfirstlane to SGPR
        const int l0 = __builtin_amdgcn_readfirstlane(sleaf[g*8 + 0]);
        const int l1 = __builtin_amdgcn_readfirstlane(sleaf[g*8 + 1]);
        const int l2 = __builtin_amdgcn_readfirstlane(sleaf[g*8 + 2]);
        const int l3 = __builtin_amdgcn_readfirstlane(sleaf[g*8 + 3]);
        const int l4 = __builtin_amdgcn_readfirstlane(sleaf[g*8 + 4]);
        const int l5 = __builtin_amdgcn_readfirstlane(sleaf[g*8 + 5]);
        const int l6 = __builtin_amdgcn_readfirstlane(sleaf[g*8 + 6]);
        const int l7 = __builtin_amdgcn_readfirstlane(sleaf[g*8 + 7]);

        // 8 leaf column gathers: 512B contiguous per wave from 0.5MB xT
        const ushort4 v0 = ((const ushort4*)(xT + (size_t)l0 * BATCH))[lane];
        const ushort4 v1 = ((const ushort4*)(xT + (size_t)l1 * BATCH))[lane];
        const ushort4 v2 = ((const ushort4*)(xT + (size_t)l2 * BATCH))[lane];
        const ushort4 v3 = ((const ushort4*)(xT + (size_t)l3 * BATCH))[lane];
        const ushort4 v4 = ((const ushort4*)(xT + (size_t)l4 * BATCH))[lane];
        const ushort4 v5 = ((const ushort4*)(xT + (size_t)l5 * BATCH))[lane];
        const ushort4 v6 = ((const ushort4*)(xT + (size_t)l6 * BATCH))[lane];
        const ushort4 v7 = ((const ushort4*)(xT + (size_t)l7 * BATCH))[lane];

        const float4 C1aa = spc[g*7 + 0];
        const float4 C1ab = spc[g*7 + 1];
        const float4 C1ba = spc[g*7 + 2];
        const float4 C1bb = spc[g*7 + 3];
        const float4 C2a  = spc[g*7 + 4];
        const float4 C2b  = spc[g*7 + 5];
        const float4 C3c  = spc[g*7 + 6];

        const float4 haa = gate4(C1aa, up4(v0), up4(v1));
        const float4 hab = gate4(C1ab, up4(v2), up4(v3));
        const float4 hba = gate4(C1ba, up4(v4), up4(v5));
        const float4 hbb = gate4(C1bb, up4(v6), up4(v7));
        const float4 h2a = gate4(C2a, haa, hab);
        const float4 h2b = gate4(C2b, hba, hbb);
        const float4 h3  = gate4(C3c, h2a, h2b);
        acc.x += h3.x; acc.y += h3.y; acc.z += h3.z; acc.w += h3.w;
    }

    // ---- block reduction + grouped atomic add
    sred[wave][lane] = acc;
    __syncthreads();
    if (wave == 0) {
        float4 t = sred[0][lane];
        #pragma unroll
        for (int w = 1; w < NWAVE; ++w) {
            float4 q = sred[w][lane];
            t.x += q.x; t.y += q.y; t.z += q.z; t.w += q.w;
        }
        const float sc = 1.0f / TAU;
        const int grp = (blockIdx.x * GPB) / GSIZE;
        const int b0 = lane * 4;
        atomicAdd(&red_out[(b0 + 0) * NGROUP + grp], t.x * sc);
        atomicAdd(&red_out[(b0 + 1) * NGROUP + grp], t.y * sc);
        atomicAdd(&red_out[(b0 + 2) * NGROUP + grp], t.z * sc);
        atomicAdd(&red_out[(b0 + 3) * NGROUP + grp], t.w * sc);
    }
}

// ---------------------------------------------------------------- launch
extern "C" void kernel_launch(void* const* d_in, const int* in_sizes, int n_in,
                              void* d_out, int out_size, void* d_ws, size_t ws_size,
                              hipStream_t stream)
{
    const float* x   = (const float*)d_in[0];
    const float* w1  = (const float*)d_in[1];
    const float* w2  = (const float*)d_in[2];
    const float* w3  = (const float*)d_in[3];
    const int*   ia1 = (const int*)d_in[4];
    const int*   ib1 = (const int*)d_in[5];
    const int*   ia2 = (const int*)d_in[6];
    const int*   ib2 = (const int*)d_in[7];
    const int*   ia3 = (const int*)d_in[8];
    const int*   ib3 = (const int*)d_in[9];
    float* out = (float*)d_out;

    // workspace: xT (0.5MB) | leaf (2MB) | pc (7MB)  ~= 9.5 MB
    char* ws = (char*)d_ws;
    ushort_t* xT = (ushort_t*)ws;
    int*    leaf = (int*)(ws + (size_t)IN_DIM * BATCH * 2);
    float4*   pc = (float4*)(leaf + (size_t)WIDTH * 8);

    hipMemsetAsync(d_out, 0, (size_t)out_size * sizeof(float), stream);

    transpose_kernel<<<64, 256, 0, stream>>>(x, xT);
    prep_kernel<<<WIDTH / 256, 256, 0, stream>>>(w1, w2, w3,
                                                 ia1, ib1, ia2, ib2, ia3, ib3,
                                                 leaf, pc);
    fused_kernel<<<NBLK, 1024, 0, stream>>>(xT, leaf, pc, out);
}

// Round 3
// 150.290 us; speedup vs baseline: 2.5199x; 2.5199x over previous
//
#include <hip/hip_runtime.h>
#include <stdint.h>

// DiffLogic: 3-layer differentiable logic network.
// Round 9: fix R8's register-spill catastrophe (VGPR=64 cap from the
// 1024-thread block forced ~550MB of scratch traffic; rocprof showed
// WRITE_SIZE=566MB on a kernel that writes 10KB).
//  - Block 512 (8 waves), __launch_bounds__(512,4): VGPR cap 128,
//    2 blocks/CU = 16 waves/CU, no artificial 64-VGPR squeeze.
//  - Keep LDS metadata staging (leaf+pc broadcast reads, one barrier).
//  - #pragma unroll 2 (the R7-proven depth): 16 gathers in flight/wave,
//    bounded liveness -> no spill.
//  - GPB=64 gates/block, grid=1000.

#define BATCH   256
#define IN_DIM  1024
#define WIDTH   64000
#define NGROUP  10
#define GSIZE   6400      // WIDTH / NGROUP
#define TAU     30.0f
#define NWAVE   8         // waves per block (512 threads)
#define GPW     8         // gates per wave
#define GPB     (NWAVE*GPW)   // 64 gates/block; 6400 % 64 == 0
#define NBLK    (WIDTH/GPB)   // 1000

typedef unsigned short ushort_t;

static __device__ __forceinline__ float bf2f(ushort_t s) {
    return __uint_as_float((uint32_t)s << 16);
}
static __device__ __forceinline__ ushort_t f2bf(float f) {   // RNE
    uint32_t u = __float_as_uint(f);
    return (ushort_t)((u + 0x7fffu + ((u >> 16) & 1u)) >> 16);
}
// h = c0 + c1*a + c2*b + c3*(a*b) = b*(c3*a+c2) + (c1*a+c0)  -- 3 FMA/elem
static __device__ __forceinline__ float gate1(float4 c, float a, float b) {
    return fmaf(b, fmaf(c.w, a, c.z), fmaf(c.y, a, c.x));
}
static __device__ __forceinline__ float4 gate4(float4 c, float4 a, float4 b) {
    float4 r;
    r.x = gate1(c, a.x, b.x);
    r.y = gate1(c, a.y, b.y);
    r.z = gate1(c, a.z, b.z);
    r.w = gate1(c, a.w, b.w);
    return r;
}
static __device__ __forceinline__ float4 up4(ushort4 s) {
    return make_float4(bf2f(s.x), bf2f(s.y), bf2f(s.z), bf2f(s.w));
}

// ---------------------------------------------------------------- transpose
// x:(256,1024) f32 row-major -> xT:(1024,256) bf16
__global__ __launch_bounds__(256) void transpose_kernel(
    const float* __restrict__ x, ushort_t* __restrict__ xT)
{
    __shared__ float tile[64][65];
    const int c0 = (blockIdx.x & 15) * 64;
    const int b0 = (blockIdx.x >> 4) * 64;
    const int lt = threadIdx.x & 63;
    const int wt = threadIdx.x >> 6;
    for (int r = wt; r < 64; r += 4)
        tile[r][lt] = x[(b0 + r) * IN_DIM + c0 + lt];
    __syncthreads();
    for (int r = wt; r < 64; r += 4)
        xT[(c0 + r) * BATCH + b0 + lt] = f2bf(tile[lt][r]);
}

// ---------------------------------------------------------------- softmax coef
static __device__ __forceinline__ float4 softmax_coef(const float* __restrict__ w)
{
    const float4* w4 = (const float4*)w;
    float4 q0 = w4[0], q1 = w4[1], q2 = w4[2], q3 = w4[3];
    float p[16] = {q0.x,q0.y,q0.z,q0.w, q1.x,q1.y,q1.z,q1.w,
                   q2.x,q2.y,q2.z,q2.w, q3.x,q3.y,q3.z,q3.w};
    float m = p[0];
    #pragma unroll
    for (int i = 1; i < 16; ++i) m = fmaxf(m, p[i]);
    float s = 0.f;
    #pragma unroll
    for (int i = 0; i < 16; ++i) { p[i] = __expf(p[i] - m); s += p[i]; }
    const float inv = 1.0f / s;
    float c0 = (p[8]+p[9]+p[10]+p[11]+p[12]+p[13]+p[14]+p[15]) * inv;
    float c1 = (p[2]+p[3]+p[6]+p[7] - p[8]-p[9]-p[12]-p[13]) * inv;
    float c2 = (p[4]+p[5]+p[6]+p[7] - p[8]-p[9]-p[10]-p[11]) * inv;
    float c3 = (p[1]-p[2]-p[4]-2.f*p[6]-p[7]+p[8]+2.f*p[9]+p[11]+p[13]-p[14]) * inv;
    return make_float4(c0, c1, c2, c3);
}

// ---------------------------------------------------------------- tree prep
// One thread per final gate j: flatten its depth-3 tree into 8 leaf x-indices
// + 7 softmaxed coefficient float4s (contiguous per gate).
__global__ __launch_bounds__(256) void prep_kernel(
    const float* __restrict__ w1, const float* __restrict__ w2,
    const float* __restrict__ w3,
    const int* __restrict__ ia1, const int* __restrict__ ib1,
    const int* __restrict__ ia2, const int* __restrict__ ib2,
    const int* __restrict__ ia3, const int* __restrict__ ib3,
    int* __restrict__ leaf,        // [WIDTH][8]
    float4* __restrict__ pc)       // [WIDTH][7]
{
    const int j = blockIdx.x * 256 + threadIdx.x;
    if (j >= WIDTH) return;

    const int pa = ia3[j], pb = ib3[j];
    const int qaa = ia2[pa], qab = ib2[pa];
    const int qba = ia2[pb], qbb = ib2[pb];

    int* L = leaf + (size_t)j * 8;
    L[0] = ia1[qaa]; L[1] = ib1[qaa];
    L[2] = ia1[qab]; L[3] = ib1[qab];
    L[4] = ia1[qba]; L[5] = ib1[qba];
    L[6] = ia1[qbb]; L[7] = ib1[qbb];

    float4* P = pc + (size_t)j * 7;
    P[0] = softmax_coef(w1 + (size_t)qaa * 16);
    P[1] = softmax_coef(w1 + (size_t)qab * 16);
    P[2] = softmax_coef(w1 + (size_t)qba * 16);
    P[3] = softmax_coef(w1 + (size_t)qbb * 16);
    P[4] = softmax_coef(w2 + (size_t)pa * 16);
    P[5] = softmax_coef(w2 + (size_t)pb * 16);
    P[6] = softmax_coef(w3 + (size_t)j * 16);
}

// ---------------------------------------------------------------- fused net
// Block = 64 contiguous gates, 8 waves. Metadata staged to LDS (coalesced,
// one barrier); gate loop unrolled x2 so ~16 gathers/wave stay in flight
// without blowing the 128-VGPR budget.
__global__ __launch_bounds__(512, 4) void fused_kernel(
    const ushort_t* __restrict__ xT,
    const int*      __restrict__ leaf,
    const float4*   __restrict__ pc,
    float*          __restrict__ red_out)
{
    __shared__ int    sleaf[GPB * 8];        // 2 KB
    __shared__ float4 spc[GPB * 7];          // 7 KB
    __shared__ float4 sred[NWAVE][64];       // 8 KB

    const int tid = threadIdx.x;

    // ---- coalesced metadata stage (block's spans are contiguous)
    sleaf[tid] = leaf[(size_t)blockIdx.x * (GPB * 8) + tid];      // 512 x 4B
    if (tid < GPB * 7)
        spc[tid] = pc[(size_t)blockIdx.x * (GPB * 7) + tid];      // 448 x 16B
    __syncthreads();

    const int lane = tid & 63;
    const int wave = tid >> 6;
    const int gbase = wave * GPW;            // gate index within block

    float4 acc = make_float4(0.f, 0.f, 0.f, 0.f);

    #pragma unroll 2
    for (int u = 0; u < GPW; ++u) {
        const int g = gbase + u;
        // LDS broadcast reads (uniform addr) -> readfirstlane to SGPR
        const int l0 = __builtin_amdgcn_readfirstlane(sleaf[g*8 + 0]);
        const int l1 = __builtin_amdgcn_readfirstlane(sleaf[g*8 + 1]);
        const int l2 = __builtin_amdgcn_readfirstlane(sleaf[g*8 + 2]);
        const int l3 = __builtin_amdgcn_readfirstlane(sleaf[g*8 + 3]);
        const int l4 = __builtin_amdgcn_readfirstlane(sleaf[g*8 + 4]);
        const int l5 = __builtin_amdgcn_readfirstlane(sleaf[g*8 + 5]);
        const int l6 = __builtin_amdgcn_readfirstlane(sleaf[g*8 + 6]);
        const int l7 = __builtin_amdgcn_readfirstlane(sleaf[g*8 + 7]);

        // 8 leaf column gathers: 512B contiguous per wave from 0.5MB xT (L2)
        const ushort4 v0 = ((const ushort4*)(xT + (size_t)l0 * BATCH))[lane];
        const ushort4 v1 = ((const ushort4*)(xT + (size_t)l1 * BATCH))[lane];
        const ushort4 v2 = ((const ushort4*)(xT + (size_t)l2 * BATCH))[lane];
        const ushort4 v3 = ((const ushort4*)(xT + (size_t)l3 * BATCH))[lane];
        const ushort4 v4 = ((const ushort4*)(xT + (size_t)l4 * BATCH))[lane];
        const ushort4 v5 = ((const ushort4*)(xT + (size_t)l5 * BATCH))[lane];
        const ushort4 v6 = ((const ushort4*)(xT + (size_t)l6 * BATCH))[lane];
        const ushort4 v7 = ((const ushort4*)(xT + (size_t)l7 * BATCH))[lane];

        const float4 C1aa = spc[g*7 + 0];
        const float4 C1ab = spc[g*7 + 1];
        const float4 C1ba = spc[g*7 + 2];
        const float4 C1bb = spc[g*7 + 3];
        const float4 C2a  = spc[g*7 + 4];
        const float4 C2b  = spc[g*7 + 5];
        const float4 C3c  = spc[g*7 + 6];

        const float4 haa = gate4(C1aa, up4(v0), up4(v1));
        const float4 hab = gate4(C1ab, up4(v2), up4(v3));
        const float4 hba = gate4(C1ba, up4(v4), up4(v5));
        const float4 hbb = gate4(C1bb, up4(v6), up4(v7));
        const float4 h2a = gate4(C2a, haa, hab);
        const float4 h2b = gate4(C2b, hba, hbb);
        const float4 h3  = gate4(C3c, h2a, h2b);
        acc.x += h3.x; acc.y += h3.y; acc.z += h3.z; acc.w += h3.w;
    }

    // ---- block reduction + grouped atomic add
    sred[wave][lane] = acc;
    __syncthreads();
    if (wave == 0) {
        float4 t = sred[0][lane];
        #pragma unroll
        for (int w = 1; w < NWAVE; ++w) {
            float4 q = sred[w][lane];
            t.x += q.x; t.y += q.y; t.z += q.z; t.w += q.w;
        }
        const float sc = 1.0f / TAU;
        const int grp = (blockIdx.x * GPB) / GSIZE;
        const int b0 = lane * 4;
        atomicAdd(&red_out[(b0 + 0) * NGROUP + grp], t.x * sc);
        atomicAdd(&red_out[(b0 + 1) * NGROUP + grp], t.y * sc);
        atomicAdd(&red_out[(b0 + 2) * NGROUP + grp], t.z * sc);
        atomicAdd(&red_out[(b0 + 3) * NGROUP + grp], t.w * sc);
    }
}

// ---------------------------------------------------------------- launch
extern "C" void kernel_launch(void* const* d_in, const int* in_sizes, int n_in,
                              void* d_out, int out_size, void* d_ws, size_t ws_size,
                              hipStream_t stream)
{
    const float* x   = (const float*)d_in[0];
    const float* w1  = (const float*)d_in[1];
    const float* w2  = (const float*)d_in[2];
    const float* w3  = (const float*)d_in[3];
    const int*   ia1 = (const int*)d_in[4];
    const int*   ib1 = (const int*)d_in[5];
    const int*   ia2 = (const int*)d_in[6];
    const int*   ib2 = (const int*)d_in[7];
    const int*   ia3 = (const int*)d_in[8];
    const int*   ib3 = (const int*)d_in[9];
    float* out = (float*)d_out;

    // workspace: xT (0.5MB) | leaf (2MB) | pc (7MB)  ~= 9.5 MB
    char* ws = (char*)d_ws;
    ushort_t* xT = (ushort_t*)ws;
    int*    leaf = (int*)(ws + (size_t)IN_DIM * BATCH * 2);
    float4*   pc = (float4*)(leaf + (size_t)WIDTH * 8);

    hipMemsetAsync(d_out, 0, (size_t)out_size * sizeof(float), stream);

    transpose_kernel<<<64, 256, 0, stream>>>(x, xT);
    prep_kernel<<<WIDTH / 256, 256, 0, stream>>>(w1, w2, w3,
                                                 ia1, ib1, ia2, ib2, ia3, ib3,
                                                 leaf, pc);
    fused_kernel<<<NBLK, 512, 0, stream>>>(xT, leaf, pc, out);
}